// Round 3
// baseline (462.338 us; speedup 1.0000x reference)
//
#include <hip/hip_runtime.h>

#define C_ 64
#define HW_ 1024
#define NE_ 4096
#define CHW_ 65536          // C_*HW_
#define ZQ_SIZE 1048576
#define LOSS_OFF ZQ_SIZE
#define IDX_OFF (ZQ_SIZE + 1)
#define EPS_GAP 2e-3f
#define LOSS_SCALE (1.25f / 1048576.f)

// monotonic float<->u64 key (score hi32, idx lo32): atomicMin == argmin w/ low-idx tie-break
__device__ __forceinline__ unsigned long long packKey(float s, int idx) {
    unsigned u = __float_as_uint(s);
    u = (u & 0x80000000u) ? ~u : (u | 0x80000000u);
    return ((unsigned long long)u << 32) | (unsigned)idx;
}
__device__ __forceinline__ float keyScore(unsigned long long k) {
    unsigned u = (unsigned)(k >> 32);
    u = (u & 0x80000000u) ? (u ^ 0x80000000u) : ~u;
    return __uint_as_float(u);
}

// merge chunk-local (s1,i1) and runner-up value s2 into global top-2 keys
__device__ __forceinline__ void mergeTop2(unsigned long long* k1,
                                          unsigned long long* k2, int row,
                                          float s1, int i1, float s2) {
    unsigned long long c = packKey(s1, i1);
    unsigned long long old = atomicMin(&k1[row], c);
    unsigned long long disp = (old > c) ? old : c;     // loser of the k1 duel
    if (disp != ~0ULL) atomicMin(&k2[row], disp);
    atomicMin(&k2[row], packKey(s2, 0x7fffffff));
}

// ---- kernel 1: h[e]=0.5||e||^2, init keys, zero loss ---------------------
__global__ void vq_prep(const float* __restrict__ emb, float* __restrict__ h,
                        unsigned long long* __restrict__ k1,
                        unsigned long long* __restrict__ k2,
                        float* __restrict__ out) {
    int t = blockIdx.x * 256 + threadIdx.x;   // 64*256 = 16384
    if (t < NE_) {
        const float4* er = (const float4*)(emb + (size_t)t * 64);
        float4 a = {0.f, 0.f, 0.f, 0.f};
#pragma unroll
        for (int k = 0; k < 16; k++) {
            float4 e4 = er[k];
            a.x = fmaf(e4.x, e4.x, a.x);
            a.y = fmaf(e4.y, e4.y, a.y);
            a.z = fmaf(e4.z, e4.z, a.z);
            a.w = fmaf(e4.w, e4.w, a.w);
        }
        h[t] = 0.5f * ((a.x + a.y) + (a.z + a.w));
    }
    k1[t] = ~0ULL;
    k2[t] = ~0ULL;
    if (t == 0) out[LOSS_OFF] = 0.f;
}

// ---- kernel 2: main scan. 16 rg x 16 ec; 4 rows/thread, 256 thr/block ----
__global__ __launch_bounds__(256, 1) void vq_scan(
        const float* __restrict__ z, const float* __restrict__ emb,
        const float* __restrict__ h,
        unsigned long long* __restrict__ k1,
        unsigned long long* __restrict__ k2) {
    __shared__ float4 se[256 * 16];   // 64 KB: 256 embeddings x 64 f32
    __shared__ float  sh[256];

    const int tid = threadIdx.x;
    const int rg = blockIdx.x >> 4;   // batch index, 1024 rows
    const int ec = blockIdx.x & 15;   // 256-embedding chunk
    const int row0 = rg * 1024 + tid; // rows: tid + {0,256,512,768}
    const float* zp = z + (size_t)rg * CHW_ + tid;

    // stage embeddings -> LDS (coalesced float4)
    const int base = ec * 256;
    const float4* src = (const float4*)(emb + (size_t)base * 64);
    for (int i = tid; i < 4096; i += 256) se[i] = src[i];
    sh[tid] = h[base + tid];

    // 4 z-rows in registers: 256 f32
    float4 zv[4][16];
#pragma unroll
    for (int r = 0; r < 4; r++) {
        const float* zr = zp + r * 256;
#pragma unroll
        for (int k = 0; k < 16; k++) {
            zv[r][k].x = zr[(4 * k + 0) * HW_];
            zv[r][k].y = zr[(4 * k + 1) * HW_];
            zv[r][k].z = zr[(4 * k + 2) * HW_];
            zv[r][k].w = zr[(4 * k + 3) * HW_];
        }
    }
    __syncthreads();

    float s1[4] = {INFINITY, INFINITY, INFINITY, INFINITY};
    float s2[4] = {INFINITY, INFINITY, INFINITY, INFINITY};
    int   i1[4] = {0, 0, 0, 0};

#pragma unroll 2
    for (int el = 0; el < 256; el++) {
        const float4* ev = &se[el * 16];
        float4 a0 = {0.f,0.f,0.f,0.f}, a1 = {0.f,0.f,0.f,0.f};
        float4 a2 = {0.f,0.f,0.f,0.f}, a3 = {0.f,0.f,0.f,0.f};
#pragma unroll
        for (int k = 0; k < 16; k++) {
            float4 e4 = ev[k];
            a0.x = fmaf(e4.x, zv[0][k].x, a0.x);
            a0.y = fmaf(e4.y, zv[0][k].y, a0.y);
            a0.z = fmaf(e4.z, zv[0][k].z, a0.z);
            a0.w = fmaf(e4.w, zv[0][k].w, a0.w);
            a1.x = fmaf(e4.x, zv[1][k].x, a1.x);
            a1.y = fmaf(e4.y, zv[1][k].y, a1.y);
            a1.z = fmaf(e4.z, zv[1][k].z, a1.z);
            a1.w = fmaf(e4.w, zv[1][k].w, a1.w);
            a2.x = fmaf(e4.x, zv[2][k].x, a2.x);
            a2.y = fmaf(e4.y, zv[2][k].y, a2.y);
            a2.z = fmaf(e4.z, zv[2][k].z, a2.z);
            a2.w = fmaf(e4.w, zv[2][k].w, a2.w);
            a3.x = fmaf(e4.x, zv[3][k].x, a3.x);
            a3.y = fmaf(e4.y, zv[3][k].y, a3.y);
            a3.z = fmaf(e4.z, zv[3][k].z, a3.z);
            a3.w = fmaf(e4.w, zv[3][k].w, a3.w);
        }
        float hh = sh[el];
        float sc0 = hh - ((a0.x + a0.y) + (a0.z + a0.w));
        float sc1 = hh - ((a1.x + a1.y) + (a1.z + a1.w));
        float sc2 = hh - ((a2.x + a2.y) + (a2.z + a2.w));
        float sc3 = hh - ((a3.x + a3.y) + (a3.z + a3.w));
        int e = base + el;
        // branchless top-2 (value-only runner-up)
        i1[0] = (sc0 < s1[0]) ? e : i1[0];
        s2[0] = fminf(s2[0], fmaxf(s1[0], sc0));
        s1[0] = fminf(s1[0], sc0);
        i1[1] = (sc1 < s1[1]) ? e : i1[1];
        s2[1] = fminf(s2[1], fmaxf(s1[1], sc1));
        s1[1] = fminf(s1[1], sc1);
        i1[2] = (sc2 < s1[2]) ? e : i1[2];
        s2[2] = fminf(s2[2], fmaxf(s1[2], sc2));
        s1[2] = fminf(s1[2], sc2);
        i1[3] = (sc3 < s1[3]) ? e : i1[3];
        s2[3] = fminf(s2[3], fmaxf(s1[3], sc3));
        s1[3] = fminf(s1[3], sc3);
    }

#pragma unroll
    for (int r = 0; r < 4; r++)
        mergeTop2(k1, k2, row0 + r * 256, s1[r], i1[r], s2[r]);
}

// ---- kernel 3: outputs; inline wave-coop fp64 rescan for near-ties -------
__global__ __launch_bounds__(64) void vq_final(
        const float* __restrict__ z, const float* __restrict__ emb,
        const unsigned long long* __restrict__ k1v,
        const unsigned long long* __restrict__ k2v,
        float* __restrict__ out) {
    int n = blockIdx.x * 64 + threadIdx.x;    // 256 blocks x 64
    unsigned long long key1 = k1v[n];
    float s1 = keyScore(key1);
    float s2 = keyScore(k2v[n]);
    int idx = (int)(unsigned)(key1 & 0xffffffffULL);

    bool ambig = (s2 - s1) < EPS_GAP;
    if (__any(ambig)) {                        // rare; zero cost when empty
        unsigned long long m = __ballot(ambig);
        const int lane = threadIdx.x & 63;
        const int wbase = blockIdx.x * 64;
        while (m) {
            int src = __ffsll((long long)m) - 1;
            m &= m - 1;
            int rn = wbase + src;
            int b = rn >> 10, hw = rn & 1023;
            const float* zrow = z + (size_t)b * CHW_ + hw;
            double best = 1e300;
            int bi = 0;
            for (int e = lane; e < NE_; e += 64) {
                const float* er = emb + (size_t)e * 64;
                double dot = 0.0, nrm = 0.0;
                for (int k = 0; k < 64; k++) {
                    double ev = (double)er[k];
                    dot = fma(ev, (double)zrow[k * HW_], dot);
                    nrm = fma(ev, ev, nrm);
                }
                double sc = 0.5 * nrm - dot;
                if (sc < best) { best = sc; bi = e; }
            }
            for (int off = 32; off; off >>= 1) {
                double ob = __shfl_xor(best, off);
                int oi = __shfl_xor(bi, off);
                if (ob < best || (ob == best && oi < bi)) { best = ob; bi = oi; }
            }
            if (lane == src) idx = bi;
        }
    }

    int b = n >> 10, hw = n & 1023;
    const float* er = emb + (size_t)idx * 64;
    float* zq = out + (size_t)b * CHW_ + hw;
    const float* zp = z + (size_t)b * CHW_ + hw;
    float lsum = 0.f;
#pragma unroll
    for (int c = 0; c < 64; c++) {
        float e = er[c];
        float d = e - zp[c * HW_];
        zq[c * HW_] = e;
        lsum = fmaf(d, d, lsum);
    }
    out[IDX_OFF + n] = (float)idx;

#pragma unroll
    for (int off = 32; off; off >>= 1) lsum += __shfl_down(lsum, off);
    if ((threadIdx.x & 63) == 0) atomicAdd(&out[LOSS_OFF], lsum * LOSS_SCALE);
}

extern "C" void kernel_launch(void* const* d_in, const int* in_sizes, int n_in,
                              void* d_out, int out_size, void* d_ws, size_t ws_size,
                              hipStream_t stream) {
    const float* z   = (const float*)d_in[0];
    const float* emb = (const float*)d_in[1];
    float* out = (float*)d_out;
    char* ws = (char*)d_ws;

    float* h               = (float*)ws;                          // 16 KB
    unsigned long long* k1 = (unsigned long long*)(ws + 16384);   // 128 KB
    unsigned long long* k2 = (unsigned long long*)(ws + 16384 + 131072); // 128 KB

    vq_prep <<<64, 256, 0, stream>>>(emb, h, k1, k2, out);
    vq_scan <<<256, 256, 0, stream>>>(z, emb, h, k1, k2);
    vq_final<<<256, 64, 0, stream>>>(z, emb, k1, k2, out);
}

// Round 4
// 58.919 us; speedup vs baseline: 7.8471x; 7.8471x over previous
//
#include <hip/hip_runtime.h>

typedef float f32x4 __attribute__((ext_vector_type(4)));
typedef short bf16x8 __attribute__((ext_vector_type(8)));

#define HW_ 1024
#define NE_ 4096
#define CHW_ 65536          // 64*1024
#define ZQ_SIZE 1048576
#define LOSS_OFF ZQ_SIZE
#define IDX_OFF (ZQ_SIZE + 1)
#define LOSS_SCALE (1.25f / 1048576.f)
#define EPS_GAP 0.125f      // on 0.5*d2 scale; covers 12-bit key truncation + bf16-split err

union FragU { unsigned u[4]; bf16x8 v; };

// split 8 f32 -> hi/lo bf16 fragments (truncation split; lo captures the tail)
__device__ __forceinline__ void split8(const float* v, FragU& hi, FragU& lo) {
#pragma unroll
    for (int p = 0; p < 4; p++) {
        float a = v[2 * p], b = v[2 * p + 1];
        unsigned ua = __float_as_uint(a), ub = __float_as_uint(b);
        hi.u[p] = (ua >> 16) | (ub & 0xFFFF0000u);
        float la = a - __uint_as_float(ua & 0xFFFF0000u);
        float lb = b - __uint_as_float(ub & 0xFFFF0000u);
        lo.u[p] = (__float_as_uint(la) >> 16) | (__float_as_uint(lb) & 0xFFFF0000u);
    }
}

// ---- kernel 1: h_e = 0.5|e|^2, h_z = 0.5|z_row|^2, init keys/loss --------
__global__ void vq_prep(const float* __restrict__ emb, const float* __restrict__ z,
                        float* __restrict__ h_e, float* __restrict__ h_z,
                        unsigned* __restrict__ k1, unsigned* __restrict__ k2,
                        float* __restrict__ out) {
    int t = blockIdx.x * 256 + threadIdx.x;   // 80*256 = 20480
    if (t < NE_) {
        const float4* er = (const float4*)(emb + (size_t)t * 64);
        float s = 0.f;
#pragma unroll
        for (int k = 0; k < 16; k++) {
            float4 e4 = er[k];
            s = fmaf(e4.x, e4.x, s); s = fmaf(e4.y, e4.y, s);
            s = fmaf(e4.z, e4.z, s); s = fmaf(e4.w, e4.w, s);
        }
        h_e[t] = 0.5f * s;
    } else {
        int n = t - NE_;                      // 0..16383
        int b = n >> 10, hw = n & 1023;
        const float* zp = z + (size_t)b * CHW_ + hw;
        float s = 0.f;
#pragma unroll
        for (int c = 0; c < 64; c++) { float v = zp[c * HW_]; s = fmaf(v, v, s); }
        h_z[n] = 0.5f * s;
        k1[n] = 0xFFFFFFFFu;
        k2[n] = 0xFFFFFFFFu;
        if (n == 0) out[LOSS_OFF] = 0.f;
    }
}

// ---- kernel 2: MFMA scan ------------------------------------------------
// Grid 512 = 8 e-chunks x 64 row-groups. Block 256 = 4 waves.
// Wave owns 8 e-tiles (128 e) register-resident (negated bf16-split frags).
// Per 16-row tile: stream z (strided f32), split, 6 mfma per e-tile.
// acc init = 0.5|z|^2 + 0.5|e|^2 ; acc += (-e).z  => acc = 0.5*d2 >= 0.
// key = (f32 bits & ~0xFFF) | e_idx ; u32 min == (score, idx) lexicographic min.
__global__ __launch_bounds__(256, 2) void vq_mfma(
        const float* __restrict__ z, const float* __restrict__ emb,
        const float* __restrict__ h_e, const float* __restrict__ h_z,
        unsigned* __restrict__ k1, unsigned* __restrict__ k2) {
    const int tid = threadIdx.x;
    const int lane = tid & 63;
    const int wave = tid >> 6;
    const int lrow = lane & 15;      // M/N index within tile
    const int lgrp = lane >> 4;      // k-octet group (0..3)
    const int ecb = blockIdx.x & 7;  // e-chunk
    const int rgb = blockIdx.x >> 3; // row-group (256 rows)

    const int ebase = ecb * 512 + wave * 128;   // wave's 128 embeddings
    const int c0 = lgrp * 8;

    // ---- load + split e-fragments (resident): 8 tiles x 2 k-steps --------
    FragU aeh[8][2], ael[8][2];
    float4 he4[8];
#pragma unroll
    for (int i = 0; i < 8; i++) {
        int eI = ebase + i * 16 + lrow;
        const float* ep = emb + (size_t)eI * 64;
#pragma unroll
        for (int s = 0; s < 2; s++) {
            float ev[8];
            const float4* e4p = (const float4*)(ep + s * 32 + c0);
            float4 ea = e4p[0], eb = e4p[1];
            ev[0] = -ea.x; ev[1] = -ea.y; ev[2] = -ea.z; ev[3] = -ea.w;
            ev[4] = -eb.x; ev[5] = -eb.y; ev[6] = -eb.z; ev[7] = -eb.w;
            split8(ev, aeh[i][s], ael[i][s]);
        }
        he4[i] = *(const float4*)(h_e + ebase + i * 16 + lgrp * 4);
    }

    // ---- scan 16 row-tiles ----------------------------------------------
    for (int rt = 0; rt < 16; rt++) {
        const int rowbase = rgb * 256 + rt * 16;
        const int b = rowbase >> 10;
        const int hw = (rowbase & 1023) + lrow;
        const float* zc = z + (size_t)b * CHW_ + hw;

        float zr[16];
#pragma unroll
        for (int s = 0; s < 2; s++)
#pragma unroll
            for (int j = 0; j < 8; j++)
                zr[s * 8 + j] = zc[(s * 32 + c0 + j) * HW_];

        FragU bzh[2], bzl[2];
        split8(zr, bzh[0], bzl[0]);
        split8(zr + 8, bzh[1], bzl[1]);

        const float hz = h_z[rowbase + lrow];
        unsigned s1k = 0xFFFFFFFFu, s2k = 0xFFFFFFFFu;

#pragma unroll
        for (int i = 0; i < 8; i++) {
            f32x4 acc;
            acc[0] = he4[i].x + hz; acc[1] = he4[i].y + hz;
            acc[2] = he4[i].z + hz; acc[3] = he4[i].w + hz;
            acc = __builtin_amdgcn_mfma_f32_16x16x32_bf16(aeh[i][0].v, bzh[0].v, acc, 0, 0, 0);
            acc = __builtin_amdgcn_mfma_f32_16x16x32_bf16(aeh[i][1].v, bzh[1].v, acc, 0, 0, 0);
            acc = __builtin_amdgcn_mfma_f32_16x16x32_bf16(ael[i][0].v, bzh[0].v, acc, 0, 0, 0);
            acc = __builtin_amdgcn_mfma_f32_16x16x32_bf16(ael[i][1].v, bzh[1].v, acc, 0, 0, 0);
            acc = __builtin_amdgcn_mfma_f32_16x16x32_bf16(aeh[i][0].v, bzl[0].v, acc, 0, 0, 0);
            acc = __builtin_amdgcn_mfma_f32_16x16x32_bf16(aeh[i][1].v, bzl[1].v, acc, 0, 0, 0);

            const unsigned eb12 = (unsigned)(ebase + i * 16 + lgrp * 4);
#pragma unroll
            for (int r = 0; r < 4; r++) {
                float sc = fmaxf(acc[r], 0.f);
                unsigned key = (__float_as_uint(sc) & 0xFFFFF000u) | (eb12 + r);
                unsigned t2 = (s1k > key) ? s1k : key;
                s2k = (s2k < t2) ? s2k : t2;
                s1k = (s1k < key) ? s1k : key;
            }
        }

        // merge across the 4 k-octet lane-groups (same z-col)
#pragma unroll
        for (int off = 16; off <= 32; off += 16) {
            unsigned o1 = (unsigned)__shfl_xor((int)s1k, off);
            unsigned o2 = (unsigned)__shfl_xor((int)s2k, off);
            unsigned t2 = (s1k > o1) ? s1k : o1;
            unsigned m2 = (s2k < o2) ? s2k : o2;
            s2k = (m2 < t2) ? m2 : t2;
            s1k = (s1k < o1) ? s1k : o1;
        }

        if (lane < 16) {
            const int n = rowbase + lane;
            unsigned old = atomicMin(&k1[n], s1k);
            unsigned disp = (old > s1k) ? old : s1k;
            atomicMin(&k2[n], disp);
            atomicMin(&k2[n], s2k);
        }
    }
}

// ---- kernel 3: outputs; exact fp64 top-2 arbitration for near-ties -------
__global__ __launch_bounds__(64) void vq_final(
        const float* __restrict__ z, const float* __restrict__ emb,
        const unsigned* __restrict__ k1v, const unsigned* __restrict__ k2v,
        float* __restrict__ out) {
    int n = blockIdx.x * 64 + threadIdx.x;    // 256 blocks x 64
    unsigned key1 = k1v[n];
    unsigned key2 = k2v[n];
    int idx = (int)(key1 & 0xFFFu);
    float s1 = __uint_as_float(key1 & 0xFFFFF000u);
    float s2 = __uint_as_float(key2 & 0xFFFFF000u);

    int b = n >> 10, hw = n & 1023;
    const float* zp = z + (size_t)b * CHW_ + hw;

    if (s2 - s1 < EPS_GAP) {                   // near-tie: exact fp64 duel
        int i2 = (int)(key2 & 0xFFFu);
        const float* ea = emb + (size_t)idx * 64;
        const float* eb = emb + (size_t)i2 * 64;
        double da = 0.0, db = 0.0;
#pragma unroll 8
        for (int c = 0; c < 64; c++) {
            double zv = (double)zp[c * HW_];
            double xa = (double)ea[c] - zv;
            double xb = (double)eb[c] - zv;
            da = fma(xa, xa, da);
            db = fma(xb, xb, db);
        }
        if (db < da || (db == da && i2 < idx)) idx = i2;
    }

    const float* er = emb + (size_t)idx * 64;
    float* zq = out + (size_t)b * CHW_ + hw;
    float lsum = 0.f;
#pragma unroll
    for (int c = 0; c < 64; c++) {
        float e = er[c];
        float d = e - zp[c * HW_];
        zq[c * HW_] = e;
        lsum = fmaf(d, d, lsum);
    }
    out[IDX_OFF + n] = (float)idx;

#pragma unroll
    for (int off = 32; off; off >>= 1) lsum += __shfl_down(lsum, off);
    if ((threadIdx.x & 63) == 0) atomicAdd(&out[LOSS_OFF], lsum * LOSS_SCALE);
}

extern "C" void kernel_launch(void* const* d_in, const int* in_sizes, int n_in,
                              void* d_out, int out_size, void* d_ws, size_t ws_size,
                              hipStream_t stream) {
    const float* z   = (const float*)d_in[0];
    const float* emb = (const float*)d_in[1];
    float* out = (float*)d_out;
    char* ws = (char*)d_ws;

    float* h_e  = (float*)ws;                       // 16 KB
    float* h_z  = (float*)(ws + 16384);             // 64 KB
    unsigned* k1 = (unsigned*)(ws + 16384 + 65536); // 64 KB
    unsigned* k2 = (unsigned*)(ws + 16384 + 65536 + 65536); // 64 KB

    vq_prep <<<80, 256, 0, stream>>>(emb, z, h_e, h_z, k1, k2, out);
    vq_mfma <<<512, 256, 0, stream>>>(z, emb, h_e, h_z, k1, k2);
    vq_final<<<256, 64, 0, stream>>>(z, emb, k1, k2, out);
}